// Round 1
// baseline (105.700 us; speedup 1.0000x reference)
//
#include <hip/hip_runtime.h>
#include <hip/hip_bf16.h>

#define N_FEAT 128

// Pass 1: per-node projection. One 64-lane wave per node; lane i covers
// features [2i, 2i+1]. Both dot products (W_src and W_trg halves) are
// reduced in one butterfly.
__global__ __launch_bounds__(256) void project_kernel(
    const float* __restrict__ x, const float* __restrict__ W,
    float* __restrict__ p_src, float* __restrict__ p_trg, int n_nodes)
{
    int gid  = blockIdx.x * blockDim.x + threadIdx.x;
    int node = gid >> 6;
    int lane = threadIdx.x & 63;
    if (node >= n_nodes) return;

    const float2 xv = *reinterpret_cast<const float2*>(x + (size_t)node * N_FEAT + 2 * lane);
    const float2 ws = *reinterpret_cast<const float2*>(W + 2 * lane);
    const float2 wt = *reinterpret_cast<const float2*>(W + N_FEAT + 2 * lane);

    float ssrc = fmaf(xv.x, ws.x, xv.y * ws.y);
    float strg = fmaf(xv.x, wt.x, xv.y * wt.y);

    #pragma unroll
    for (int off = 32; off > 0; off >>= 1) {
        ssrc += __shfl_down(ssrc, off, 64);
        strg += __shfl_down(strg, off, 64);
    }
    if (lane == 0) {
        p_src[node] = ssrc;
        p_trg[node] = strg;
    }
}

// Pass 2: per-edge gather of the two scalar projections + sigmoid.
__global__ __launch_bounds__(256) void edge_kernel(
    const int* __restrict__ esrc, const int* __restrict__ etrg,
    const float* __restrict__ p_src, const float* __restrict__ p_trg,
    const float* __restrict__ b, float* __restrict__ out, int n_edges)
{
    int e = blockIdx.x * blockDim.x + threadIdx.x;
    if (e >= n_edges) return;
    float logit = p_src[esrc[e]] + p_trg[etrg[e]] + b[0];
    out[e] = 1.0f / (1.0f + __expf(-logit));
}

extern "C" void kernel_launch(void* const* d_in, const int* in_sizes, int n_in,
                              void* d_out, int out_size, void* d_ws, size_t ws_size,
                              hipStream_t stream)
{
    // setup_inputs() dict order: input, edge_src_nodes, edge_trg_nodes, W, b
    const float* x    = (const float*)d_in[0];
    const int*   esrc = (const int*)d_in[1];
    const int*   etrg = (const int*)d_in[2];
    const float* W    = (const float*)d_in[3];
    const float* b    = (const float*)d_in[4];
    float* out = (float*)d_out;

    int n_nodes = in_sizes[0] / N_FEAT;   // 100000
    int n_edges = in_sizes[1];            // 640000

    float* p_src = (float*)d_ws;          // n_nodes floats
    float* p_trg = p_src + n_nodes;       // n_nodes floats (total 800 KB << ws)

    const int threads = 256;
    int waves_per_block = threads / 64;   // 4 nodes per block
    int blocks1 = (n_nodes + waves_per_block - 1) / waves_per_block;
    project_kernel<<<blocks1, threads, 0, stream>>>(x, W, p_src, p_trg, n_nodes);

    int blocks2 = (n_edges + threads - 1) / threads;
    edge_kernel<<<blocks2, threads, 0, stream>>>(esrc, etrg, p_src, p_trg, b, out, n_edges);
}

// Round 2
// 99.081 us; speedup vs baseline: 1.0668x; 1.0668x over previous
//
#include <hip/hip_runtime.h>
#include <hip/hip_bf16.h>

#define N_FEAT 128

// Pass 1: per-node projection, p_src[n] = x[n]·W[0,:128], p_trg[n] = x[n]·W[0,128:].
// 32 lanes per node, float4 (16 B) loads per lane — coalescing sweet spot.
// Each 64-lane wave covers 2 consecutive nodes; reduction is 5 shfl steps
// confined to 32-lane segments.
__global__ __launch_bounds__(256) void project_kernel(
    const float* __restrict__ x, const float* __restrict__ W,
    float* __restrict__ p_src, float* __restrict__ p_trg, int n_nodes)
{
    int gid  = blockIdx.x * blockDim.x + threadIdx.x;
    int node = gid >> 5;           // 32 lanes per node
    int sub  = threadIdx.x & 31;   // lane within the 32-lane segment
    if (node >= n_nodes) return;

    const float4 xv = *reinterpret_cast<const float4*>(x + (size_t)node * N_FEAT + 4 * sub);
    const float4 ws = *reinterpret_cast<const float4*>(W + 4 * sub);            // W_src slice
    const float4 wt = *reinterpret_cast<const float4*>(W + N_FEAT + 4 * sub);   // W_trg slice

    float ssrc = fmaf(xv.x, ws.x, fmaf(xv.y, ws.y, fmaf(xv.z, ws.z, xv.w * ws.w)));
    float strg = fmaf(xv.x, wt.x, fmaf(xv.y, wt.y, fmaf(xv.z, wt.z, xv.w * wt.w)));

    #pragma unroll
    for (int off = 16; off > 0; off >>= 1) {
        ssrc += __shfl_down(ssrc, off, 32);   // width 32: stays within the segment
        strg += __shfl_down(strg, off, 32);
    }
    if (sub == 0) {
        p_src[node] = ssrc;
        p_trg[node] = strg;
    }
}

// Pass 2: 4 edges per thread. int4 index loads, scalar L2-resident gathers,
// float4 output store.
__global__ __launch_bounds__(256) void edge_kernel(
    const int* __restrict__ esrc, const int* __restrict__ etrg,
    const float* __restrict__ p_src, const float* __restrict__ p_trg,
    const float* __restrict__ b, float* __restrict__ out, int n_edges4)
{
    int i = blockIdx.x * blockDim.x + threadIdx.x;
    if (i >= n_edges4) return;
    const int4 s = reinterpret_cast<const int4*>(esrc)[i];
    const int4 t = reinterpret_cast<const int4*>(etrg)[i];
    const float bias = b[0];

    float4 o;
    o.x = 1.0f / (1.0f + __expf(-(p_src[s.x] + p_trg[t.x] + bias)));
    o.y = 1.0f / (1.0f + __expf(-(p_src[s.y] + p_trg[t.y] + bias)));
    o.z = 1.0f / (1.0f + __expf(-(p_src[s.z] + p_trg[t.z] + bias)));
    o.w = 1.0f / (1.0f + __expf(-(p_src[s.w] + p_trg[t.w] + bias)));
    reinterpret_cast<float4*>(out)[i] = o;
}

extern "C" void kernel_launch(void* const* d_in, const int* in_sizes, int n_in,
                              void* d_out, int out_size, void* d_ws, size_t ws_size,
                              hipStream_t stream)
{
    // setup_inputs() dict order: input, edge_src_nodes, edge_trg_nodes, W, b
    const float* x    = (const float*)d_in[0];
    const int*   esrc = (const int*)d_in[1];
    const int*   etrg = (const int*)d_in[2];
    const float* W    = (const float*)d_in[3];
    const float* b    = (const float*)d_in[4];
    float* out = (float*)d_out;

    int n_nodes = in_sizes[0] / N_FEAT;   // 100000
    int n_edges = in_sizes[1];            // 640000 (divisible by 4)

    float* p_src = (float*)d_ws;          // n_nodes floats
    float* p_trg = p_src + n_nodes;       // n_nodes floats

    const int threads = 256;
    // 32 lanes per node -> 8 nodes per 256-thread block
    int blocks1 = (n_nodes * 32 + threads - 1) / threads;
    project_kernel<<<blocks1, threads, 0, stream>>>(x, W, p_src, p_trg, n_nodes);

    int n_edges4 = n_edges / 4;           // 160000
    int blocks2 = (n_edges4 + threads - 1) / threads;
    edge_kernel<<<blocks2, threads, 0, stream>>>(esrc, etrg, p_src, p_trg, b, out, n_edges4);
}